// Round 1
// baseline (79.623 us; speedup 1.0000x reference)
//
#include <hip/hip_runtime.h>
#include <hip/hip_bf16.h>

#define NN 512

// ---------------- Kernel 1: S = P * P^T (fp32 vector GEMM, 32x32 tiles) --------
__global__ __launch_bounds__(256) void sap_gemm(const float* __restrict__ P,
                                                float* __restrict__ S) {
    __shared__ float As[32][33];
    __shared__ float Bs[32][33];
    const int t  = threadIdx.x;
    const int tx = t & 15, ty = t >> 4;
    const int i0 = blockIdx.y * 32, j0 = blockIdx.x * 32;

    float acc00 = 0.f, acc01 = 0.f, acc10 = 0.f, acc11 = 0.f;

    const int lr = t >> 3;        // 0..31 (tile row for staging)
    const int lc = (t & 7) * 4;   // 0,4,...,28 (tile col for staging, float4)

    for (int kt = 0; kt < NN; kt += 32) {
        float4 a = *(const float4*)&P[(i0 + lr) * NN + kt + lc];
        float4 b = *(const float4*)&P[(j0 + lr) * NN + kt + lc];
        As[lr][lc + 0] = a.x; As[lr][lc + 1] = a.y;
        As[lr][lc + 2] = a.z; As[lr][lc + 3] = a.w;
        Bs[lr][lc + 0] = b.x; Bs[lr][lc + 1] = b.y;
        Bs[lr][lc + 2] = b.z; Bs[lr][lc + 3] = b.w;
        __syncthreads();
#pragma unroll
        for (int kk = 0; kk < 32; kk++) {
            float a0 = As[2 * ty][kk],     a1 = As[2 * ty + 1][kk];
            float b0 = Bs[2 * tx][kk],     b1 = Bs[2 * tx + 1][kk];
            acc00 += a0 * b0; acc01 += a0 * b1;
            acc10 += a1 * b0; acc11 += a1 * b1;
        }
        __syncthreads();
    }
    const int i = i0 + 2 * ty, j = j0 + 2 * tx;
    S[i * NN + j]           = acc00;
    S[i * NN + j + 1]       = acc01;
    S[(i + 1) * NN + j]     = acc10;
    S[(i + 1) * NN + j + 1] = acc11;
}

// ---------------- Kernel 2: per-anchor SmoothAP row ---------------------------
// One block per anchor row i. Only j with same label (plus j==i) contribute:
// sim_pos_rk[i,j] = eye + I_pos*(1+pos_sum); everything else is 0 in the j-sum.
__global__ __launch_bounds__(256) void sap_rows(const float* __restrict__ S,
                                               const int* __restrict__ labels,
                                               float* __restrict__ per_anchor) {
    __shared__ float srow[NN];
    __shared__ float posf[NN];
    __shared__ int   poslist[NN];
    __shared__ int   npos_cnt;
    __shared__ float wave_part[4];

    const int i = blockIdx.x;
    const int t = threadIdx.x;
    if (t == 0) npos_cnt = 0;
    if (t < 4) wave_part[t] = 0.f;
    __syncthreads();

    const int li = labels[i];
    for (int k = t; k < NN; k += 256) {
        srow[k] = S[i * NN + k];
        bool p  = (labels[k] == li) && (k != i);
        posf[k] = p ? 1.f : 0.f;
        if (p) {
            int idx = atomicAdd(&npos_cnt, 1);
            poslist[idx] = k;
        }
    }
    __syncthreads();

    const int cnt = npos_cnt;              // positives excluding self
    if (cnt == 0) {                        // n_pos == 1 -> per_anchor = 0
        if (t == 0) per_anchor[i] = 0.f;
        return;
    }

    const int wave = t >> 6, lane = t & 63;
    // sigmoid(clip(x/T,-50,50)) = 1/(1+exp2(clip(-x*100*log2e, +-50*log2e)))
    const float C1   = 100.0f * 1.44269504088896340736f;
    const float CLIP = 50.0f * 1.44269504088896340736f;

    float acc = 0.f;   // lane-0-only accumulation of num/den over this wave's j's
    for (int idx = wave; idx <= cnt; idx += 4) {   // idx==cnt means j==i (the eye term)
        const int   j   = (idx == cnt) ? i : poslist[idx];
        const float sij = srow[j];
        float sum_all = 0.f, sum_pos = 0.f;
#pragma unroll
        for (int kk = 0; kk < 8; kk++) {
            const int   k  = lane + (kk << 6);
            float y = (sij - srow[k]) * C1;
            y = fminf(fmaxf(y, -CLIP), CLIP);
            float tt = 1.0f / (1.0f + exp2f(y));
            if (k == j) tt = 0.f;                  // (1-eye)[j,k] factor
            sum_all += tt;
            sum_pos += tt * posf[k];               // posf[i]==0 excludes k==i
        }
#pragma unroll
        for (int off = 32; off; off >>= 1) {
            sum_all += __shfl_down(sum_all, off);
            sum_pos += __shfl_down(sum_pos, off);
        }
        if (lane == 0) {
            const float den = 1.0f + sum_all;
            const float num = (j == i) ? 1.0f : (1.0f + sum_pos);
            acc += num / den;
        }
    }
    if (lane == 0) wave_part[wave] = acc;   // note: waves that skipped loop wrote 0 above... overwrite ok
    __syncthreads();
    if (t == 0) {
        float tot = wave_part[0] + wave_part[1] + wave_part[2] + wave_part[3];
        per_anchor[i] = tot / (float)(cnt + 1);
    }
}

// ---------------- Kernel 3: final reduce --------------------------------------
__global__ __launch_bounds__(256) void sap_reduce(const float* __restrict__ per_anchor,
                                                  float* __restrict__ out) {
    __shared__ float sh[256];
    const int t = threadIdx.x;
    sh[t] = per_anchor[t] + per_anchor[t + 256];
    __syncthreads();
    for (int s = 128; s; s >>= 1) {
        if (t < s) sh[t] += sh[t + s];
        __syncthreads();
    }
    if (t == 0) out[0] = 1.0f - sh[0] / (float)NN;
}

extern "C" void kernel_launch(void* const* d_in, const int* in_sizes, int n_in,
                              void* d_out, int out_size, void* d_ws, size_t ws_size,
                              hipStream_t stream) {
    const float* preds  = (const float*)d_in[0];
    const int*   labels = (const int*)d_in[1];
    float* out = (float*)d_out;

    float* S          = (float*)d_ws;                       // 512*512 floats = 1 MB
    float* per_anchor = (float*)d_ws + NN * NN;             // 512 floats

    dim3 ggrid(NN / 32, NN / 32);
    sap_gemm<<<ggrid, 256, 0, stream>>>(preds, S);
    sap_rows<<<NN, 256, 0, stream>>>(S, labels, per_anchor);
    sap_reduce<<<1, 256, 0, stream>>>(per_anchor, out);
}